// Round 1
// baseline (22026.183 us; speedup 1.0000x reference)
//
#include <hip/hip_runtime.h>

#define NBLOCKS 256
#define NTHREADS 256
#define B_ 256
#define T_ 80
#define IN_ 39
#define H_ 256
#define G_ 1024
#define L_ 5
#define TC_ 16
#define NCH_ 5

#define XP_FLOATS (B_ * TC_ * G_)          // 4,194,304 floats = 16 MB
#define HBUF_FLOATS (B_ * T_ * H_)         // 5,242,880 floats = 20 MB
#define BAR_BYTE_OFF ((size_t)(XP_FLOATS + HBUF_FLOATS) * 4)  // 37,748,736

// Device-wide barrier: agent-scope atomics + threadfence (cross-XCD safe).
__device__ __forceinline__ void gbar(int* cnt, int* gen) {
    __syncthreads();
    if (threadIdx.x == 0) {
        __threadfence();  // flush this block's writes to coherence point
        int g = __hip_atomic_load(gen, __ATOMIC_RELAXED, __HIP_MEMORY_SCOPE_AGENT);
        int old = __hip_atomic_fetch_add(cnt, 1, __ATOMIC_RELAXED, __HIP_MEMORY_SCOPE_AGENT);
        if (old == NBLOCKS - 1) {
            __hip_atomic_store(cnt, 0, __ATOMIC_RELAXED, __HIP_MEMORY_SCOPE_AGENT);
            __hip_atomic_store(gen, g + 1, __ATOMIC_RELEASE, __HIP_MEMORY_SCOPE_AGENT);
        } else {
            while (__hip_atomic_load(gen, __ATOMIC_RELAXED, __HIP_MEMORY_SCOPE_AGENT) <= g) {
                __builtin_amdgcn_s_sleep(4);
            }
            __threadfence();  // invalidate caches before reading others' data
        }
    }
    __syncthreads();
}

extern "C" __global__ void __launch_bounds__(NTHREADS)
lstm_all(const float* __restrict__ x, const float* __restrict__ Wih0,
         const float* __restrict__ Wihr, const float* __restrict__ Whh,
         const float* __restrict__ bih, const float* __restrict__ bhh,
         const float* __restrict__ fcw, const float* __restrict__ fcb,
         float* __restrict__ out, float* __restrict__ ws)
{
    __shared__ float smem[4224];  // recur: 16 rows x 264 (padded); proj: 2 x [16][68]

    float* xp = ws;                      // [B*TC][G]  (per-chunk projection)
    float* hbuf = ws + XP_FLOATS;        // [B*T][H]   (layer output, reused across layers)
    int* bcnt = (int*)(ws + XP_FLOATS + HBUF_FLOATS);
    int* bgen = bcnt + 1;

    const int tid = threadIdx.x;
    const int bid = blockIdx.x;
    const int tx = tid & 15, ty = tid >> 4;     // 16x16 thread grid
    const int lr = tid >> 2, lc4 = (tid & 3) << 2;  // loader roles

    // recurrence roles: block -> (btile, jtile); thread -> (b = btile*16+ty, j = jtile*16+tx)
    const int btile = bid >> 4, jtile = bid & 15;
    const int bg = btile * 16 + ty;
    const int jg = jtile * 16 + tx;

    for (int l = 0; l < L_; ++l) {
        const int K = (l == 0) ? IN_ : H_;
        const float* Wih = (l == 0) ? Wih0 : (Wihr + (size_t)(l - 1) * G_ * H_);
        const float4* W0 = (const float4*)(Whh + ((size_t)l * G_ + 0 * H_ + jg) * H_);
        const float4* W1 = (const float4*)(Whh + ((size_t)l * G_ + 1 * H_ + jg) * H_);
        const float4* W2 = (const float4*)(Whh + ((size_t)l * G_ + 2 * H_ + jg) * H_);
        const float4* W3 = (const float4*)(Whh + ((size_t)l * G_ + 3 * H_ + jg) * H_);
        float creg = 0.0f;

        for (int ch = 0; ch < NCH_; ++ch) {
            const int t0 = ch * TC_;

            // ---------------- projection: xp[b*TC+tt][g] = X(t0+tt) . Wih[g] + bias ----
            {
                float* As = smem;          // [16][68] : As[kk][row]
                float* Bs = smem + 1088;   // [16][68] : Bs[kk][col]
                for (int tile = bid; tile < 1024; tile += NBLOCKS) {  // 64 mt x 16 nt
                    const int mt = tile >> 4;
                    const int nt = tile & 15;
                    const int ar = mt * 64 + lr;
                    const int ab = ar >> 4;
                    const int at = t0 + (ar & 15);
                    const float* arow = (l == 0)
                        ? (x + ((size_t)ab * T_ + at) * IN_)
                        : (hbuf + ((size_t)ab * T_ + at) * H_);
                    const float* brow = Wih + (size_t)(nt * 64 + lr) * K;

                    float acc[4][4];
                    #pragma unroll
                    for (int i = 0; i < 4; ++i)
                        #pragma unroll
                        for (int j = 0; j < 4; ++j) acc[i][j] = 0.0f;

                    for (int k0 = 0; k0 < K; k0 += 16) {
                        __syncthreads();
                        if (l == 0) {  // K=39, stride 39: scalar + bounds
                            #pragma unroll
                            for (int i = 0; i < 4; ++i) {
                                int k = k0 + lc4 + i;
                                As[(lc4 + i) * 68 + lr] = (k < IN_) ? arow[k] : 0.0f;
                                Bs[(lc4 + i) * 68 + lr] = (k < IN_) ? brow[k] : 0.0f;
                            }
                        } else {       // K=256: float4 loads
                            float4 av = *(const float4*)(arow + k0 + lc4);
                            float4 bv = *(const float4*)(brow + k0 + lc4);
                            As[(lc4 + 0) * 68 + lr] = av.x;
                            As[(lc4 + 1) * 68 + lr] = av.y;
                            As[(lc4 + 2) * 68 + lr] = av.z;
                            As[(lc4 + 3) * 68 + lr] = av.w;
                            Bs[(lc4 + 0) * 68 + lr] = bv.x;
                            Bs[(lc4 + 1) * 68 + lr] = bv.y;
                            Bs[(lc4 + 2) * 68 + lr] = bv.z;
                            Bs[(lc4 + 3) * 68 + lr] = bv.w;
                        }
                        __syncthreads();
                        #pragma unroll
                        for (int kk = 0; kk < 16; ++kk) {
                            float4 a4 = *(const float4*)&As[kk * 68 + ty * 4];
                            float4 b4 = *(const float4*)&Bs[kk * 68 + tx * 4];
                            acc[0][0] += a4.x * b4.x; acc[0][1] += a4.x * b4.y;
                            acc[0][2] += a4.x * b4.z; acc[0][3] += a4.x * b4.w;
                            acc[1][0] += a4.y * b4.x; acc[1][1] += a4.y * b4.y;
                            acc[1][2] += a4.y * b4.z; acc[1][3] += a4.y * b4.w;
                            acc[2][0] += a4.z * b4.x; acc[2][1] += a4.z * b4.y;
                            acc[2][2] += a4.z * b4.z; acc[2][3] += a4.z * b4.w;
                            acc[3][0] += a4.w * b4.x; acc[3][1] += a4.w * b4.y;
                            acc[3][2] += a4.w * b4.z; acc[3][3] += a4.w * b4.w;
                        }
                    }
                    const int col = nt * 64 + tx * 4;
                    const float bs0 = bih[l * G_ + col + 0] + bhh[l * G_ + col + 0];
                    const float bs1 = bih[l * G_ + col + 1] + bhh[l * G_ + col + 1];
                    const float bs2 = bih[l * G_ + col + 2] + bhh[l * G_ + col + 2];
                    const float bs3 = bih[l * G_ + col + 3] + bhh[l * G_ + col + 3];
                    #pragma unroll
                    for (int i = 0; i < 4; ++i) {
                        const int row = mt * 64 + ty * 4 + i;
                        float4 o;
                        o.x = acc[i][0] + bs0; o.y = acc[i][1] + bs1;
                        o.z = acc[i][2] + bs2; o.w = acc[i][3] + bs3;
                        *(float4*)&xp[(size_t)row * G_ + col] = o;
                    }
                }
            }
            gbar(bcnt, bgen);

            // ---------------- recurrence over this chunk ----------------
            for (int tt = 0; tt < TC_; ++tt) {
                const int t = t0 + tt;
                if (t > 0) {
                    // stage h(t-1) rows for this block's 16 batches: [16][264]
                    const float* src = hbuf + ((size_t)(btile * 16 + ty) * T_ + (t - 1)) * H_ + tx * 16;
                    float4* dst = (float4*)&smem[ty * 264 + tx * 16];
                    const float4* s4 = (const float4*)src;
                    dst[0] = s4[0]; dst[1] = s4[1]; dst[2] = s4[2]; dst[3] = s4[3];
                }
                __syncthreads();

                const size_t xrow = ((size_t)bg * TC_ + tt) * G_;
                float g0 = xp[xrow + 0 * H_ + jg];
                float g1 = xp[xrow + 1 * H_ + jg];
                float g2 = xp[xrow + 2 * H_ + jg];
                float g3 = xp[xrow + 3 * H_ + jg];

                if (t > 0) {
                    const float4* hv = (const float4*)&smem[ty * 264];
                    #pragma unroll 8
                    for (int k4 = 0; k4 < 64; ++k4) {
                        float4 h4 = hv[k4];
                        float4 a = W0[k4];
                        g0 += h4.x * a.x + h4.y * a.y + h4.z * a.z + h4.w * a.w;
                        float4 b = W1[k4];
                        g1 += h4.x * b.x + h4.y * b.y + h4.z * b.z + h4.w * b.w;
                        float4 c = W2[k4];
                        g2 += h4.x * c.x + h4.y * c.y + h4.z * c.z + h4.w * c.w;
                        float4 d = W3[k4];
                        g3 += h4.x * d.x + h4.y * d.y + h4.z * d.z + h4.w * d.w;
                    }
                }
                const float I = 1.0f / (1.0f + expf(-g0));
                const float F = 1.0f / (1.0f + expf(-g1));
                const float Gt = tanhf(g2);
                const float O = 1.0f / (1.0f + expf(-g3));
                creg = F * creg + I * Gt;
                const float hval = O * tanhf(creg);
                hbuf[((size_t)bg * T_ + t) * H_ + jg] = hval;

                gbar(bcnt, bgen);
            }
        }
    }

    // ---------------- final FC: out[b][t] = h4[b][t][:] . fcw + fcb ----------------
    if (tid < 64) ((float4*)smem)[tid] = ((const float4*)fcw)[tid];
    __syncthreads();
    if (tid < T_) {
        const int t = tid;
        const float4* h4p = (const float4*)(hbuf + ((size_t)bid * T_ + t) * H_);
        const float4* w4p = (const float4*)smem;
        float acc = fcb[0];
        #pragma unroll 8
        for (int k4 = 0; k4 < 64; ++k4) {
            float4 h4 = h4p[k4], w4 = w4p[k4];
            acc += h4.x * w4.x + h4.y * w4.y + h4.z * w4.z + h4.w * w4.w;
        }
        out[bid * T_ + t] = acc;
    }
}

extern "C" void kernel_launch(void* const* d_in, const int* in_sizes, int n_in,
                              void* d_out, int out_size, void* d_ws, size_t ws_size,
                              hipStream_t stream) {
    (void)in_sizes; (void)n_in; (void)out_size; (void)ws_size;
    const float* x    = (const float*)d_in[0];
    const float* Wih0 = (const float*)d_in[1];
    const float* Wihr = (const float*)d_in[2];
    const float* Whh  = (const float*)d_in[3];
    const float* bih  = (const float*)d_in[4];
    const float* bhh  = (const float*)d_in[5];
    const float* fcw  = (const float*)d_in[6];
    const float* fcb  = (const float*)d_in[7];
    float* out = (float*)d_out;
    float* ws  = (float*)d_ws;

    // barrier counters must start at 0 every launch (ws is poisoned 0xAA)
    hipMemsetAsync((char*)d_ws + BAR_BYTE_OFF, 0, 256, stream);
    hipLaunchKernelGGL(lstm_all, dim3(NBLOCKS), dim3(NTHREADS), 0, stream,
                       x, Wih0, Wihr, Whh, bih, bhh, fcw, fcb, out, ws);
}

// Round 2
// 10695.321 us; speedup vs baseline: 2.0594x; 2.0594x over previous
//
#include <hip/hip_runtime.h>

#define B_ 256
#define T_ 80
#define IN_ 39
#define H_ 256
#define G_ 1024
#define L_ 5
#define TC_ 16
#define NCH_ 5

#define XP_FLOATS (B_ * TC_ * G_)      // 4,194,304 floats = 16 MB
#define HBUF_FLOATS (B_ * T_ * H_)     // 5,242,880 floats = 20 MB
#define CBUF_FLOATS (B_ * H_)          // 65,536 floats
#define WT_FLOATS (L_ * G_ * H_)       // 1,310,720 floats = 5 MB

// ---------------- W_hh transpose: Wt[l][k][row] = Whh[l][row][k] ----------------
extern "C" __global__ void __launch_bounds__(256)
wt_kernel(const float* __restrict__ Whh, float* __restrict__ Wt) {
    const int gid = blockIdx.x * 256 + threadIdx.x;   // 5*262144 total
    const int l = gid >> 18;
    const int rem = gid & 262143;
    const int k = rem >> 10;
    const int r = rem & 1023;
    Wt[gid] = Whh[((size_t)l << 18) + ((size_t)r << 8) + k];
}

// ---------------- projection GEMM: one 64x64 tile per block ----------------
extern "C" __global__ void __launch_bounds__(256)
proj_kernel(const float* __restrict__ src, const float* __restrict__ Wih,
            const float* __restrict__ bihl, const float* __restrict__ bhhl,
            float* __restrict__ xp, int K, int t0) {
    __shared__ float As[16 * 68];
    __shared__ float Bs[16 * 68];
    const int tid = threadIdx.x;
    const int mt = blockIdx.x >> 4, nt = blockIdx.x & 15;
    const int tx = tid & 15, ty = tid >> 4;
    const int lr = tid >> 2, lc4 = (tid & 3) << 2;

    const int ar = mt * 64 + lr;
    const int ab = ar >> 4;
    const int at = t0 + (ar & 15);
    const float* arow = src + ((size_t)ab * T_ + at) * K;
    const float* brow = Wih + (size_t)(nt * 64 + lr) * K;

    float acc[4][4];
    #pragma unroll
    for (int i = 0; i < 4; ++i)
        #pragma unroll
        for (int j = 0; j < 4; ++j) acc[i][j] = 0.0f;

    for (int k0 = 0; k0 < K; k0 += 16) {
        __syncthreads();
        if (K == IN_) {  // K=39: scalar + bounds
            #pragma unroll
            for (int i = 0; i < 4; ++i) {
                int k = k0 + lc4 + i;
                As[(lc4 + i) * 68 + lr] = (k < IN_) ? arow[k] : 0.0f;
                Bs[(lc4 + i) * 68 + lr] = (k < IN_) ? brow[k] : 0.0f;
            }
        } else {         // K=256: float4
            float4 av = *(const float4*)(arow + k0 + lc4);
            float4 bv = *(const float4*)(brow + k0 + lc4);
            As[(lc4 + 0) * 68 + lr] = av.x;
            As[(lc4 + 1) * 68 + lr] = av.y;
            As[(lc4 + 2) * 68 + lr] = av.z;
            As[(lc4 + 3) * 68 + lr] = av.w;
            Bs[(lc4 + 0) * 68 + lr] = bv.x;
            Bs[(lc4 + 1) * 68 + lr] = bv.y;
            Bs[(lc4 + 2) * 68 + lr] = bv.z;
            Bs[(lc4 + 3) * 68 + lr] = bv.w;
        }
        __syncthreads();
        #pragma unroll
        for (int kk = 0; kk < 16; ++kk) {
            float4 a4 = *(const float4*)&As[kk * 68 + ty * 4];
            float4 b4 = *(const float4*)&Bs[kk * 68 + tx * 4];
            acc[0][0] += a4.x * b4.x; acc[0][1] += a4.x * b4.y;
            acc[0][2] += a4.x * b4.z; acc[0][3] += a4.x * b4.w;
            acc[1][0] += a4.y * b4.x; acc[1][1] += a4.y * b4.y;
            acc[1][2] += a4.y * b4.z; acc[1][3] += a4.y * b4.w;
            acc[2][0] += a4.z * b4.x; acc[2][1] += a4.z * b4.y;
            acc[2][2] += a4.z * b4.z; acc[2][3] += a4.z * b4.w;
            acc[3][0] += a4.w * b4.x; acc[3][1] += a4.w * b4.y;
            acc[3][2] += a4.w * b4.z; acc[3][3] += a4.w * b4.w;
        }
    }
    const int col = nt * 64 + tx * 4;
    const float bs0 = bihl[col + 0] + bhhl[col + 0];
    const float bs1 = bihl[col + 1] + bhhl[col + 1];
    const float bs2 = bihl[col + 2] + bhhl[col + 2];
    const float bs3 = bihl[col + 3] + bhhl[col + 3];
    #pragma unroll
    for (int i = 0; i < 4; ++i) {
        const int row = mt * 64 + ty * 4 + i;
        float4 o;
        o.x = acc[i][0] + bs0; o.y = acc[i][1] + bs1;
        o.z = acc[i][2] + bs2; o.w = acc[i][3] + bs3;
        *(float4*)&xp[(size_t)row * G_ + col] = o;
    }
}

// ---------------- recurrence: 16 steps, 2 batches per block, coalesced Wt ----------------
__device__ __forceinline__ float sigm(float x) { return 1.0f / (1.0f + expf(-x)); }

extern "C" __global__ void __launch_bounds__(256)
rec_kernel(const float* __restrict__ xp, const float* __restrict__ Wt_l,
           float* __restrict__ hbuf, float* __restrict__ cbuf, int t0, int first) {
    __shared__ float h_lds[2][256];
    __shared__ float c_lds[2][256];
    __shared__ float part[256 * 33];   // [(kq*64+jq)*33 + (b*16+g*4+i)]

    const int tid = threadIdx.x;
    const int jq = tid & 63;       // hidden-col quad: cols jq*4..jq*4+3
    const int kq = tid >> 6;       // k-slice: k in [kq*64, kq*64+64)
    const int bg = blockIdx.x * 2; // two global batches: bg, bg+1

    // init h(t0-1), c
    if (tid < 128) {
        const int b = tid >> 6, q = tid & 63;
        float4 h0, c0;
        if (first) {
            h0 = make_float4(0.f, 0.f, 0.f, 0.f);
            c0 = make_float4(0.f, 0.f, 0.f, 0.f);
        } else {
            h0 = *(const float4*)&hbuf[((size_t)(bg + b) * T_ + (t0 - 1)) * H_ + q * 4];
            c0 = *(const float4*)&cbuf[(size_t)(bg + b) * H_ + q * 4];
        }
        *(float4*)&h_lds[b][q * 4] = h0;
        *(float4*)&c_lds[b][q * 4] = c0;
    }
    __syncthreads();

    const float* Wp = Wt_l + (size_t)(kq * 64) * G_ + jq * 4;

    for (int tt = 0; tt < TC_; ++tt) {
        const int t = t0 + tt;

        // main: partial gates over this thread's k-slice, both batches
        float acc[2][4][4];
        #pragma unroll
        for (int b = 0; b < 2; ++b)
            #pragma unroll
            for (int g = 0; g < 4; ++g)
                #pragma unroll
                for (int i = 0; i < 4; ++i) acc[b][g][i] = 0.0f;

        #pragma unroll 4
        for (int kk = 0; kk < 64; ++kk) {
            const int k = kq * 64 + kk;
            const float h0 = h_lds[0][k];
            const float h1 = h_lds[1][k];
            const float* wrow = Wp + (size_t)kk * G_;
            #pragma unroll
            for (int g = 0; g < 4; ++g) {
                float4 w = *(const float4*)(wrow + g * 256);
                acc[0][g][0] += h0 * w.x; acc[0][g][1] += h0 * w.y;
                acc[0][g][2] += h0 * w.z; acc[0][g][3] += h0 * w.w;
                acc[1][g][0] += h1 * w.x; acc[1][g][1] += h1 * w.y;
                acc[1][g][2] += h1 * w.z; acc[1][g][3] += h1 * w.w;
            }
        }
        float* pp = &part[tid * 33];
        #pragma unroll
        for (int b = 0; b < 2; ++b)
            #pragma unroll
            for (int g = 0; g < 4; ++g)
                #pragma unroll
                for (int i = 0; i < 4; ++i) pp[b * 16 + g * 4 + i] = acc[b][g][i];
        __syncthreads();

        // finish: 128 threads = (b, hidden-quad)
        if (tid < 128) {
            const int b = tid >> 6, q = tid & 63;
            const int bb = bg + b;
            const size_t xrow = ((size_t)bb * TC_ + tt) * G_;
            float g4[4][4];
            #pragma unroll
            for (int g = 0; g < 4; ++g) {
                float4 xv = *(const float4*)&xp[xrow + g * 256 + q * 4];
                g4[g][0] = xv.x; g4[g][1] = xv.y; g4[g][2] = xv.z; g4[g][3] = xv.w;
            }
            #pragma unroll
            for (int k2 = 0; k2 < 4; ++k2) {
                const float* ps = &part[(k2 * 64 + q) * 33 + b * 16];
                #pragma unroll
                for (int g = 0; g < 4; ++g)
                    #pragma unroll
                    for (int i = 0; i < 4; ++i) g4[g][i] += ps[g * 4 + i];
            }
            float4 cv = *(float4*)&c_lds[b][q * 4];
            float c[4] = {cv.x, cv.y, cv.z, cv.w};
            float hv[4];
            #pragma unroll
            for (int i = 0; i < 4; ++i) {
                const float I = sigm(g4[0][i]);
                const float F = sigm(g4[1][i]);
                const float Gt = tanhf(g4[2][i]);
                const float O = sigm(g4[3][i]);
                c[i] = F * c[i] + I * Gt;
                hv[i] = O * tanhf(c[i]);
            }
            *(float4*)&c_lds[b][q * 4] = make_float4(c[0], c[1], c[2], c[3]);
            float4 hq = make_float4(hv[0], hv[1], hv[2], hv[3]);
            *(float4*)&h_lds[b][q * 4] = hq;
            *(float4*)&hbuf[((size_t)bb * T_ + t) * H_ + q * 4] = hq;
        }
        __syncthreads();
    }

    // persist c for next chunk
    if (tid < 128) {
        const int b = tid >> 6, q = tid & 63;
        *(float4*)&cbuf[(size_t)(bg + b) * H_ + q * 4] = *(float4*)&c_lds[b][q * 4];
    }
}

// ---------------- final FC ----------------
extern "C" __global__ void __launch_bounds__(128)
fc_kernel(const float* __restrict__ hbuf, const float* __restrict__ fcw,
          const float* __restrict__ fcb, float* __restrict__ out) {
    __shared__ float wsm[256];
    const int tid = threadIdx.x;
    const int b = blockIdx.x;
    if (tid < 64) ((float4*)wsm)[tid] = ((const float4*)fcw)[tid];
    __syncthreads();
    if (tid < T_) {
        const float4* h4p = (const float4*)(hbuf + ((size_t)b * T_ + tid) * H_);
        const float4* w4p = (const float4*)wsm;
        float acc = fcb[0];
        #pragma unroll 8
        for (int k4 = 0; k4 < 64; ++k4) {
            float4 h4 = h4p[k4], w4 = w4p[k4];
            acc += h4.x * w4.x + h4.y * w4.y + h4.z * w4.z + h4.w * w4.w;
        }
        out[b * T_ + tid] = acc;
    }
}

extern "C" void kernel_launch(void* const* d_in, const int* in_sizes, int n_in,
                              void* d_out, int out_size, void* d_ws, size_t ws_size,
                              hipStream_t stream) {
    (void)in_sizes; (void)n_in; (void)out_size; (void)ws_size;
    const float* x    = (const float*)d_in[0];
    const float* Wih0 = (const float*)d_in[1];
    const float* Wihr = (const float*)d_in[2];
    const float* Whh  = (const float*)d_in[3];
    const float* bih  = (const float*)d_in[4];
    const float* bhh  = (const float*)d_in[5];
    const float* fcw  = (const float*)d_in[6];
    const float* fcb  = (const float*)d_in[7];
    float* out = (float*)d_out;
    float* ws  = (float*)d_ws;

    float* xp   = ws;
    float* hbuf = ws + XP_FLOATS;
    float* cbuf = hbuf + HBUF_FLOATS;
    float* wt   = cbuf + CBUF_FLOATS;

    hipLaunchKernelGGL(wt_kernel, dim3(WT_FLOATS / 256), dim3(256), 0, stream, Whh, wt);

    for (int l = 0; l < L_; ++l) {
        const int K = (l == 0) ? IN_ : H_;
        const float* src = (l == 0) ? x : hbuf;
        const float* Wih = (l == 0) ? Wih0 : (Wihr + (size_t)(l - 1) * G_ * H_);
        const float* Wt_l = wt + (size_t)l * G_ * H_;
        for (int ch = 0; ch < NCH_; ++ch) {
            const int t0 = ch * TC_;
            hipLaunchKernelGGL(proj_kernel, dim3(1024), dim3(256), 0, stream,
                               src, Wih, bih + l * G_, bhh + l * G_, xp, K, t0);
            hipLaunchKernelGGL(rec_kernel, dim3(128), dim3(256), 0, stream,
                               xp, Wt_l, hbuf, cbuf, t0, ch == 0 ? 1 : 0);
        }
    }
    hipLaunchKernelGGL(fc_kernel, dim3(B_), dim3(128), 0, stream, hbuf, fcw, fcb, out);
}

// Round 3
// 4849.924 us; speedup vs baseline: 4.5416x; 2.2053x over previous
//
#include <hip/hip_runtime.h>

#define B_ 256
#define T_ 80
#define IN_ 39
#define H_ 256
#define G_ 1024
#define L_ 5
#define TC_ 16
#define NCH_ 5

#define XP_FLOATS   (B_ * TC_ * G_)     // 4,194,304
#define HBUF_FLOATS (B_ * T_ * H_)      // 5,242,880
#define CBUF_FLOATS (B_ * H_)           // 65,536
#define WG_FLOATS   (L_ * G_ * H_)      // 1,310,720
#define HX_FLOATS   (2 * 32 * 2048)     // 131,072
#define CNT_OFF_FLOATS (XP_FLOATS + HBUF_FLOATS + CBUF_FLOATS + WG_FLOATS + HX_FLOATS)

#define AG __HIP_MEMORY_SCOPE_AGENT

__device__ __forceinline__ float sigm(float x) { return 1.0f / (1.0f + expf(-x)); }
__device__ __forceinline__ void fma4(float4& a, float s, const float4& w) {
    a.x = fmaf(s, w.x, a.x); a.y = fmaf(s, w.y, a.y);
    a.z = fmaf(s, w.z, a.z); a.w = fmaf(s, w.w, a.w);
}
__device__ __forceinline__ void red4(float4& a) {
    a.x += __shfl_xor(a.x, 32); a.y += __shfl_xor(a.y, 32);
    a.z += __shfl_xor(a.z, 32); a.w += __shfl_xor(a.w, 32);
}
__device__ __forceinline__ float lo32(unsigned long long v) { return __uint_as_float((unsigned)v); }
__device__ __forceinline__ float hi32(unsigned long long v) { return __uint_as_float((unsigned)(v >> 32)); }

// ---- Wg: per-slice interleaved W_hh: Wg[l][s][k][j][g] = Whh[l][g*256+s*32+j][k] ----
extern "C" __global__ void __launch_bounds__(256)
wt_kernel(const float* __restrict__ Whh, float* __restrict__ Wg) {
    const int gid = blockIdx.x * 256 + threadIdx.x;
    const int g4 = gid & 3;
    const int j  = (gid >> 2) & 31;
    const int k  = (gid >> 7) & 255;
    const int s  = (gid >> 15) & 7;
    const int l  = gid >> 18;
    Wg[gid] = Whh[((size_t)(l * 1024 + g4 * 256 + s * 32 + j)) * 256 + k];
}

// ---- projection GEMM (unchanged from round 2) ----
extern "C" __global__ void __launch_bounds__(256)
proj_kernel(const float* __restrict__ src, const float* __restrict__ Wih,
            const float* __restrict__ bihl, const float* __restrict__ bhhl,
            float* __restrict__ xp, int K, int t0) {
    __shared__ float As[16 * 68];
    __shared__ float Bs[16 * 68];
    const int tid = threadIdx.x;
    const int mt = blockIdx.x >> 4, nt = blockIdx.x & 15;
    const int tx = tid & 15, ty = tid >> 4;
    const int lr = tid >> 2, lc4 = (tid & 3) << 2;

    const int ar = mt * 64 + lr;
    const int ab = ar >> 4;
    const int at = t0 + (ar & 15);
    const float* arow = src + ((size_t)ab * T_ + at) * K;
    const float* brow = Wih + (size_t)(nt * 64 + lr) * K;

    float acc[4][4];
    #pragma unroll
    for (int i = 0; i < 4; ++i)
        #pragma unroll
        for (int j = 0; j < 4; ++j) acc[i][j] = 0.0f;

    for (int k0 = 0; k0 < K; k0 += 16) {
        __syncthreads();
        if (K == IN_) {
            #pragma unroll
            for (int i = 0; i < 4; ++i) {
                int k = k0 + lc4 + i;
                As[(lc4 + i) * 68 + lr] = (k < IN_) ? arow[k] : 0.0f;
                Bs[(lc4 + i) * 68 + lr] = (k < IN_) ? brow[k] : 0.0f;
            }
        } else {
            float4 av = *(const float4*)(arow + k0 + lc4);
            float4 bv = *(const float4*)(brow + k0 + lc4);
            As[(lc4 + 0) * 68 + lr] = av.x;
            As[(lc4 + 1) * 68 + lr] = av.y;
            As[(lc4 + 2) * 68 + lr] = av.z;
            As[(lc4 + 3) * 68 + lr] = av.w;
            Bs[(lc4 + 0) * 68 + lr] = bv.x;
            Bs[(lc4 + 1) * 68 + lr] = bv.y;
            Bs[(lc4 + 2) * 68 + lr] = bv.z;
            Bs[(lc4 + 3) * 68 + lr] = bv.w;
        }
        __syncthreads();
        #pragma unroll
        for (int kk = 0; kk < 16; ++kk) {
            float4 a4 = *(const float4*)&As[kk * 68 + ty * 4];
            float4 b4 = *(const float4*)&Bs[kk * 68 + tx * 4];
            acc[0][0] += a4.x * b4.x; acc[0][1] += a4.x * b4.y;
            acc[0][2] += a4.x * b4.z; acc[0][3] += a4.x * b4.w;
            acc[1][0] += a4.y * b4.x; acc[1][1] += a4.y * b4.y;
            acc[1][2] += a4.y * b4.z; acc[1][3] += a4.y * b4.w;
            acc[2][0] += a4.z * b4.x; acc[2][1] += a4.z * b4.y;
            acc[2][2] += a4.z * b4.z; acc[2][3] += a4.z * b4.w;
            acc[3][0] += a4.w * b4.x; acc[3][1] += a4.w * b4.y;
            acc[3][2] += a4.w * b4.z; acc[3][3] += a4.w * b4.w;
        }
    }
    const int col = nt * 64 + tx * 4;
    const float bs0 = bihl[col + 0] + bhhl[col + 0];
    const float bs1 = bihl[col + 1] + bhhl[col + 1];
    const float bs2 = bihl[col + 2] + bhhl[col + 2];
    const float bs3 = bihl[col + 3] + bhhl[col + 3];
    #pragma unroll
    for (int i = 0; i < 4; ++i) {
        const int row = mt * 64 + ty * 4 + i;
        float4 o;
        o.x = acc[i][0] + bs0; o.y = acc[i][1] + bs1;
        o.z = acc[i][2] + bs2; o.w = acc[i][3] + bs3;
        *(float4*)&xp[(size_t)row * G_ + col] = o;
    }
}

// ---- recurrence: W-stationary in LDS, gate-split, 8-block group sync ----
// grid 256 = 32 groups (8 batches) x 8 slices (32 units x 4 gates).
// LDS: W slice 128KB + hT[256][8] 8KB + part[4][32][36] 18KB = 157,696 B -> 1 block/CU.
extern "C" __global__ void __launch_bounds__(256, 1)
rec2_kernel(const float* __restrict__ xp, const float* __restrict__ Wg_l,
            float* __restrict__ hbuf, float* __restrict__ cbuf,
            float* __restrict__ hx, int* __restrict__ cnt,
            int t0, int chkb, int first) {
    extern __shared__ float smem[];
    float* sW = smem;            // 32768 floats: [k][j][g]
    float* sH = smem + 32768;    // 2048 floats: hT[k][bb]
    float* sP = smem + 34816;    // 4608 floats: part[w][jj][36]

    const int tid = threadIdx.x;
    const int bid = blockIdx.x;
    const int grp = bid & 31;
    const int s   = bid >> 5;
    const int jj  = tid & 31;   // main identity: unit
    const int ks  = tid >> 5;   // main identity: k-slice
    const int w   = tid >> 6;   // wave id
    const int fb  = tid >> 5;   // finish identity: batch
    const int fj  = tid & 31;   // finish identity: unit
    const int bglob = grp * 8 + fb;
    const int unit  = s * 32 + fj;
    int* cnt_g = cnt + grp;

    // load W slice into LDS (coalesced, linear)
    {
        const float4* Wgs = (const float4*)Wg_l + (size_t)s * 8192;
        float4* sW4 = (float4*)sW;
        #pragma unroll 4
        for (int i = tid; i < 8192; i += 256) sW4[i] = Wgs[i];
    }

    float creg = first ? 0.0f : cbuf[(size_t)bglob * H_ + unit];
    const float4* sW4 = (const float4*)sW;

    for (int tt = 0; tt < TC_; ++tt) {
        const int t = t0 + tt;

        // ---- phase A: sync-in + gather h(t-1) into sH (hT[k][bb]) ----
        if (tt == 0) {
            if (first) {
                for (int i = tid; i < 2048; i += 256) sH[i] = 0.0f;
            } else {
                const int u = tid;
                #pragma unroll
                for (int bb = 0; bb < 8; ++bb)
                    sH[u * 8 + bb] = hbuf[((size_t)(grp * 8 + bb) * T_ + (t0 - 1)) * H_ + u];
            }
        } else {
            if (tid == 0) {
                const int tgt = 8 * (chkb + tt);
                while (__hip_atomic_load(cnt_g, __ATOMIC_RELAXED, AG) < tgt)
                    __builtin_amdgcn_s_sleep(1);
                (void)__hip_atomic_load(cnt_g, __ATOMIC_ACQUIRE, AG);
            }
            __syncthreads();
            const unsigned long long* hs =
                (const unsigned long long*)(hx + (size_t)(((tt - 1) & 1) * 32 + grp) * 2048);
            const int u = tid;
            unsigned long long v0 = __hip_atomic_load(hs + u * 4 + 0, __ATOMIC_RELAXED, AG);
            unsigned long long v1 = __hip_atomic_load(hs + u * 4 + 1, __ATOMIC_RELAXED, AG);
            unsigned long long v2 = __hip_atomic_load(hs + u * 4 + 2, __ATOMIC_RELAXED, AG);
            unsigned long long v3 = __hip_atomic_load(hs + u * 4 + 3, __ATOMIC_RELAXED, AG);
            float4 fa, fbv;
            fa.x = lo32(v0); fa.y = hi32(v0); fa.z = lo32(v1); fa.w = hi32(v1);
            fbv.x = lo32(v2); fbv.y = hi32(v2); fbv.z = lo32(v3); fbv.w = hi32(v3);
            *(float4*)&sH[u * 8] = fa;
            *(float4*)&sH[u * 8 + 4] = fbv;
        }

        // xp prefetch (finish identity; consumed in phase C)
        const size_t xrow = ((size_t)bglob * TC_ + tt) * G_ + unit;
        const float x0 = xp[xrow];
        const float x1 = xp[xrow + 256];
        const float x2 = xp[xrow + 512];
        const float x3 = xp[xrow + 768];

        __syncthreads();  // (b) sH ready

        // ---- phase B: main k-loop, all from LDS ----
        float4 a0 = {0,0,0,0}, a1 = {0,0,0,0}, a2 = {0,0,0,0}, a3 = {0,0,0,0};
        float4 a4 = {0,0,0,0}, a5 = {0,0,0,0}, a6 = {0,0,0,0}, a7 = {0,0,0,0};
        #pragma unroll 4
        for (int kk = 0; kk < 32; ++kk) {
            const int k = ks * 32 + kk;
            const float4 wv = sW4[k * 32 + jj];
            const float4 ha = *(const float4*)&sH[k * 8];
            const float4 hb = *(const float4*)&sH[k * 8 + 4];
            fma4(a0, ha.x, wv); fma4(a1, ha.y, wv);
            fma4(a2, ha.z, wv); fma4(a3, ha.w, wv);
            fma4(a4, hb.x, wv); fma4(a5, hb.y, wv);
            fma4(a6, hb.z, wv); fma4(a7, hb.w, wv);
        }
        // reduce ks-pairs within wave
        red4(a0); red4(a1); red4(a2); red4(a3);
        red4(a4); red4(a5); red4(a6); red4(a7);
        if ((tid & 63) < 32) {
            float4* pp = (float4*)&sP[(w * 32 + jj) * 36];
            pp[0] = a0; pp[1] = a1; pp[2] = a2; pp[3] = a3;
            pp[4] = a4; pp[5] = a5; pp[6] = a6; pp[7] = a7;
        }
        __syncthreads();  // (c) partials ready

        // ---- phase C: finish ----
        float4 g4;
        g4.x = x0; g4.y = x1; g4.z = x2; g4.w = x3;
        #pragma unroll
        for (int w2 = 0; w2 < 4; ++w2) {
            const float4 pw = *(const float4*)&sP[(w2 * 32 + fj) * 36 + fb * 4];
            g4.x += pw.x; g4.y += pw.y; g4.z += pw.z; g4.w += pw.w;
        }
        const float I = sigm(g4.x);
        const float F = sigm(g4.y);
        const float Gt = tanhf(g4.z);
        const float O = sigm(g4.w);
        creg = F * creg + I * Gt;
        const float hval = O * tanhf(creg);
        hbuf[((size_t)bglob * T_ + t) * H_ + unit] = hval;

        if (tt < TC_ - 1) {
            __hip_atomic_store(hx + (size_t)((tt & 1) * 32 + grp) * 2048 + unit * 8 + fb,
                               hval, __ATOMIC_RELAXED, AG);
            asm volatile("s_waitcnt vmcnt(0)" ::: "memory");
            __syncthreads();  // (d) all stores drained
            if (tid == 0)
                __hip_atomic_fetch_add(cnt_g, 1, __ATOMIC_RELEASE, AG);
        }
    }

    cbuf[(size_t)bglob * H_ + unit] = creg;
}

// ---- final FC ----
extern "C" __global__ void __launch_bounds__(128)
fc_kernel(const float* __restrict__ hbuf, const float* __restrict__ fcw,
          const float* __restrict__ fcb, float* __restrict__ out) {
    __shared__ float wsm[256];
    const int tid = threadIdx.x;
    const int b = blockIdx.x;
    if (tid < 64) ((float4*)wsm)[tid] = ((const float4*)fcw)[tid];
    __syncthreads();
    if (tid < T_) {
        const float4* h4p = (const float4*)(hbuf + ((size_t)b * T_ + tid) * H_);
        const float4* w4p = (const float4*)wsm;
        float acc = fcb[0];
        #pragma unroll 8
        for (int k4 = 0; k4 < 64; ++k4) {
            float4 h4 = h4p[k4], w4 = w4p[k4];
            acc += h4.x * w4.x + h4.y * w4.y + h4.z * w4.z + h4.w * w4.w;
        }
        out[b * T_ + tid] = acc;
    }
}

extern "C" void kernel_launch(void* const* d_in, const int* in_sizes, int n_in,
                              void* d_out, int out_size, void* d_ws, size_t ws_size,
                              hipStream_t stream) {
    (void)in_sizes; (void)n_in; (void)out_size; (void)ws_size;
    const float* x    = (const float*)d_in[0];
    const float* Wih0 = (const float*)d_in[1];
    const float* Wihr = (const float*)d_in[2];
    const float* Whh  = (const float*)d_in[3];
    const float* bih  = (const float*)d_in[4];
    const float* bhh  = (const float*)d_in[5];
    const float* fcw  = (const float*)d_in[6];
    const float* fcb  = (const float*)d_in[7];
    float* out = (float*)d_out;
    float* ws  = (float*)d_ws;

    float* xp   = ws;
    float* hbuf = ws + XP_FLOATS;
    float* cbuf = hbuf + HBUF_FLOATS;
    float* wg   = cbuf + CBUF_FLOATS;
    float* hx   = wg + WG_FLOATS;
    int*   cnt  = (int*)(ws + CNT_OFF_FLOATS);

    hipMemsetAsync(cnt, 0, 128, stream);
    hipLaunchKernelGGL(wt_kernel, dim3(WG_FLOATS / 256), dim3(256), 0, stream, Whh, wg);

    for (int l = 0; l < L_; ++l) {
        const int K = (l == 0) ? IN_ : H_;
        const float* src = (l == 0) ? x : hbuf;
        const float* Wih = (l == 0) ? Wih0 : (Wihr + (size_t)(l - 1) * G_ * H_);
        const float* Wg_l = wg + (size_t)l * (G_ * H_);
        for (int ch = 0; ch < NCH_; ++ch) {
            const int t0 = ch * TC_;
            const int chkb = (l * NCH_ + ch) * (TC_ - 1);
            hipLaunchKernelGGL(proj_kernel, dim3(1024), dim3(256), 0, stream,
                               src, Wih, bih + l * G_, bhh + l * G_, xp, K, t0);
            hipLaunchKernelGGL(rec2_kernel, dim3(256), dim3(256), 157696, stream,
                               xp, Wg_l, hbuf, cbuf, hx, cnt, t0, chkb, ch == 0 ? 1 : 0);
        }
    }
    hipLaunchKernelGGL(fc_kernel, dim3(B_), dim3(128), 0, stream, hbuf, fcw, fcb, out);
}

// Round 4
// 2687.951 us; speedup vs baseline: 8.1944x; 1.8043x over previous
//
#include <hip/hip_runtime.h>

#define B_ 256
#define T_ 80
#define IN_ 39
#define H_ 256
#define G_ 1024
#define L_ 5
#define TC_ 16
#define NCH_ 5

#define XP_FLOATS   (B_ * TC_ * G_)     // 4,194,304
#define HBUF_FLOATS (B_ * T_ * H_)      // 5,242,880
#define CBUF_FLOATS (B_ * H_)           // 65,536
#define WG_FLOATS   (L_ * G_ * H_)      // 1,310,720
#define HX_FLOATS   (2 * 32 * 2048)     // 131,072
#define CNT_OFF_FLOATS (XP_FLOATS + HBUF_FLOATS + CBUF_FLOATS + WG_FLOATS + HX_FLOATS)

#define AG __HIP_MEMORY_SCOPE_AGENT

__device__ __forceinline__ float sigm(float x) { return 1.0f / (1.0f + expf(-x)); }
__device__ __forceinline__ void fma4(float4& a, float s, const float4& w) {
    a.x = fmaf(s, w.x, a.x); a.y = fmaf(s, w.y, a.y);
    a.z = fmaf(s, w.z, a.z); a.w = fmaf(s, w.w, a.w);
}
__device__ __forceinline__ void red4(float4& a) {
    a.x += __shfl_xor(a.x, 32); a.y += __shfl_xor(a.y, 32);
    a.z += __shfl_xor(a.z, 32); a.w += __shfl_xor(a.w, 32);
}
__device__ __forceinline__ float lo32(unsigned long long v) { return __uint_as_float((unsigned)v); }
__device__ __forceinline__ float hi32(unsigned long long v) { return __uint_as_float((unsigned)(v >> 32)); }

// ---- Wg: per-slice interleaved W_hh: Wg[l][s][k][j][g] = Whh[l][g*256+s*32+j][k] ----
extern "C" __global__ void __launch_bounds__(256)
wt_kernel(const float* __restrict__ Whh, float* __restrict__ Wg) {
    const int gid = blockIdx.x * 256 + threadIdx.x;
    const int g4 = gid & 3;
    const int j  = (gid >> 2) & 31;
    const int k  = (gid >> 7) & 255;
    const int s  = (gid >> 15) & 7;
    const int l  = gid >> 18;
    Wg[gid] = Whh[((size_t)(l * 1024 + g4 * 256 + s * 32 + j)) * 256 + k];
}

// ---- projection GEMM (unchanged) ----
extern "C" __global__ void __launch_bounds__(256)
proj_kernel(const float* __restrict__ src, const float* __restrict__ Wih,
            const float* __restrict__ bihl, const float* __restrict__ bhhl,
            float* __restrict__ xp, int K, int t0) {
    __shared__ float As[16 * 68];
    __shared__ float Bs[16 * 68];
    const int tid = threadIdx.x;
    const int mt = blockIdx.x >> 4, nt = blockIdx.x & 15;
    const int tx = tid & 15, ty = tid >> 4;
    const int lr = tid >> 2, lc4 = (tid & 3) << 2;

    const int ar = mt * 64 + lr;
    const int ab = ar >> 4;
    const int at = t0 + (ar & 15);
    const float* arow = src + ((size_t)ab * T_ + at) * K;
    const float* brow = Wih + (size_t)(nt * 64 + lr) * K;

    float acc[4][4];
    #pragma unroll
    for (int i = 0; i < 4; ++i)
        #pragma unroll
        for (int j = 0; j < 4; ++j) acc[i][j] = 0.0f;

    for (int k0 = 0; k0 < K; k0 += 16) {
        __syncthreads();
        if (K == IN_) {
            #pragma unroll
            for (int i = 0; i < 4; ++i) {
                int k = k0 + lc4 + i;
                As[(lc4 + i) * 68 + lr] = (k < IN_) ? arow[k] : 0.0f;
                Bs[(lc4 + i) * 68 + lr] = (k < IN_) ? brow[k] : 0.0f;
            }
        } else {
            float4 av = *(const float4*)(arow + k0 + lc4);
            float4 bv = *(const float4*)(brow + k0 + lc4);
            As[(lc4 + 0) * 68 + lr] = av.x;
            As[(lc4 + 1) * 68 + lr] = av.y;
            As[(lc4 + 2) * 68 + lr] = av.z;
            As[(lc4 + 3) * 68 + lr] = av.w;
            Bs[(lc4 + 0) * 68 + lr] = bv.x;
            Bs[(lc4 + 1) * 68 + lr] = bv.y;
            Bs[(lc4 + 2) * 68 + lr] = bv.z;
            Bs[(lc4 + 3) * 68 + lr] = bv.w;
        }
        __syncthreads();
        #pragma unroll
        for (int kk = 0; kk < 16; ++kk) {
            float4 a4 = *(const float4*)&As[kk * 68 + ty * 4];
            float4 b4 = *(const float4*)&Bs[kk * 68 + tx * 4];
            acc[0][0] += a4.x * b4.x; acc[0][1] += a4.x * b4.y;
            acc[0][2] += a4.x * b4.z; acc[0][3] += a4.x * b4.w;
            acc[1][0] += a4.y * b4.x; acc[1][1] += a4.y * b4.y;
            acc[1][2] += a4.y * b4.z; acc[1][3] += a4.y * b4.w;
            acc[2][0] += a4.z * b4.x; acc[2][1] += a4.z * b4.y;
            acc[2][2] += a4.z * b4.z; acc[2][3] += a4.z * b4.w;
            acc[3][0] += a4.w * b4.x; acc[3][1] += a4.w * b4.y;
            acc[3][2] += a4.w * b4.z; acc[3][3] += a4.w * b4.w;
        }
    }
    const int col = nt * 64 + tx * 4;
    const float bs0 = bihl[col + 0] + bhhl[col + 0];
    const float bs1 = bihl[col + 1] + bhhl[col + 1];
    const float bs2 = bihl[col + 2] + bhhl[col + 2];
    const float bs3 = bihl[col + 3] + bhhl[col + 3];
    #pragma unroll
    for (int i = 0; i < 4; ++i) {
        const int row = mt * 64 + ty * 4 + i;
        float4 o;
        o.x = acc[i][0] + bs0; o.y = acc[i][1] + bs1;
        o.z = acc[i][2] + bs2; o.w = acc[i][3] + bs3;
        *(float4*)&xp[(size_t)row * G_ + col] = o;
    }
}

// ---- recurrence: W-stationary in LDS, gate-split, 8-block group sync ----
// Sync uses ONLY relaxed agent-scope (sc1) atomics: data goes through the
// coherence point per-instruction; no buffer_inv / buffer_wbl2 cache-wide ops.
// Ordering: producers drain vmcnt(0) before __syncthreads, then tid0 bumps the
// counter -> a consumer observing the counter via sc1 load also observes h.
extern "C" __global__ void __launch_bounds__(256, 1)
rec2_kernel(const float* __restrict__ xp, const float* __restrict__ Wg_l,
            float* __restrict__ hbuf, float* __restrict__ cbuf,
            float* __restrict__ hx, int* __restrict__ cnt,
            int t0, int chkb, int first) {
    extern __shared__ float smem[];
    float* sW = smem;            // 32768 floats: [k][j][g]
    float* sH = smem + 32768;    // 2048 floats: hT[k][bb]
    float* sP = smem + 34816;    // 4608 floats: part[w][jj][36]

    const int tid = threadIdx.x;
    const int bid = blockIdx.x;
    const int grp = bid & 31;
    const int s   = bid >> 5;
    const int jj  = tid & 31;   // main identity: unit
    const int ks  = tid >> 5;   // main identity: k-slice
    const int w   = tid >> 6;   // wave id
    const int fb  = tid >> 5;   // finish identity: batch
    const int fj  = tid & 31;   // finish identity: unit
    const int bglob = grp * 8 + fb;
    const int unit  = s * 32 + fj;
    int* cnt_g = cnt + grp * 32;   // one counter per 128B line

    // load W slice into LDS (coalesced, linear)
    {
        const float4* Wgs = (const float4*)Wg_l + (size_t)s * 8192;
        float4* sW4 = (float4*)sW;
        #pragma unroll 4
        for (int i = tid; i < 8192; i += 256) sW4[i] = Wgs[i];
    }

    float creg = first ? 0.0f : cbuf[(size_t)bglob * H_ + unit];
    const float4* sW4 = (const float4*)sW;

    for (int tt = 0; tt < TC_; ++tt) {
        const int t = t0 + tt;

        // ---- phase A: sync-in + gather h(t-1) into sH (hT[k][bb]) ----
        if (tt == 0) {
            if (first) {
                for (int i = tid; i < 2048; i += 256) sH[i] = 0.0f;
            } else {
                const int u = tid;
                #pragma unroll
                for (int bb = 0; bb < 8; ++bb)
                    sH[u * 8 + bb] = hbuf[((size_t)(grp * 8 + bb) * T_ + (t0 - 1)) * H_ + u];
            }
        } else {
            if (tid == 0) {
                const int tgt = 8 * (chkb + tt);
                while (__hip_atomic_load(cnt_g, __ATOMIC_RELAXED, AG) < tgt)
                    __builtin_amdgcn_s_sleep(1);
            }
            __syncthreads();
            const unsigned long long* hs =
                (const unsigned long long*)(hx + (size_t)(((tt - 1) & 1) * 32 + grp) * 2048);
            const int u = tid;
            unsigned long long v0 = __hip_atomic_load(hs + u * 4 + 0, __ATOMIC_RELAXED, AG);
            unsigned long long v1 = __hip_atomic_load(hs + u * 4 + 1, __ATOMIC_RELAXED, AG);
            unsigned long long v2 = __hip_atomic_load(hs + u * 4 + 2, __ATOMIC_RELAXED, AG);
            unsigned long long v3 = __hip_atomic_load(hs + u * 4 + 3, __ATOMIC_RELAXED, AG);
            float4 fa, fbv;
            fa.x = lo32(v0); fa.y = hi32(v0); fa.z = lo32(v1); fa.w = hi32(v1);
            fbv.x = lo32(v2); fbv.y = hi32(v2); fbv.z = lo32(v3); fbv.w = hi32(v3);
            *(float4*)&sH[u * 8] = fa;
            *(float4*)&sH[u * 8 + 4] = fbv;
        }

        // xp prefetch (finish identity; consumed in phase C)
        const size_t xrow = ((size_t)bglob * TC_ + tt) * G_ + unit;
        const float x0 = xp[xrow];
        const float x1 = xp[xrow + 256];
        const float x2 = xp[xrow + 512];
        const float x3 = xp[xrow + 768];

        __syncthreads();  // (b) sH ready

        // ---- phase B: main k-loop, all from LDS ----
        float4 a0 = {0,0,0,0}, a1 = {0,0,0,0}, a2 = {0,0,0,0}, a3 = {0,0,0,0};
        float4 a4 = {0,0,0,0}, a5 = {0,0,0,0}, a6 = {0,0,0,0}, a7 = {0,0,0,0};
        #pragma unroll 4
        for (int kk = 0; kk < 32; ++kk) {
            const int k = ks * 32 + kk;
            const float4 wv = sW4[k * 32 + jj];
            const float4 ha = *(const float4*)&sH[k * 8];
            const float4 hb = *(const float4*)&sH[k * 8 + 4];
            fma4(a0, ha.x, wv); fma4(a1, ha.y, wv);
            fma4(a2, ha.z, wv); fma4(a3, ha.w, wv);
            fma4(a4, hb.x, wv); fma4(a5, hb.y, wv);
            fma4(a6, hb.z, wv); fma4(a7, hb.w, wv);
        }
        // reduce ks-pairs within wave
        red4(a0); red4(a1); red4(a2); red4(a3);
        red4(a4); red4(a5); red4(a6); red4(a7);
        if ((tid & 63) < 32) {
            float4* pp = (float4*)&sP[(w * 32 + jj) * 36];
            pp[0] = a0; pp[1] = a1; pp[2] = a2; pp[3] = a3;
            pp[4] = a4; pp[5] = a5; pp[6] = a6; pp[7] = a7;
        }
        __syncthreads();  // (c) partials ready

        // ---- phase C: finish ----
        float4 g4;
        g4.x = x0; g4.y = x1; g4.z = x2; g4.w = x3;
        #pragma unroll
        for (int w2 = 0; w2 < 4; ++w2) {
            const float4 pw = *(const float4*)&sP[(w2 * 32 + fj) * 36 + fb * 4];
            g4.x += pw.x; g4.y += pw.y; g4.z += pw.z; g4.w += pw.w;
        }
        const float I = sigm(g4.x);
        const float F = sigm(g4.y);
        const float Gt = tanhf(g4.z);
        const float O = sigm(g4.w);
        creg = F * creg + I * Gt;
        const float hval = O * tanhf(creg);
        hbuf[((size_t)bglob * T_ + t) * H_ + unit] = hval;

        if (tt < TC_ - 1) {
            __hip_atomic_store(hx + (size_t)((tt & 1) * 32 + grp) * 2048 + unit * 8 + fb,
                               hval, __ATOMIC_RELAXED, AG);
            asm volatile("s_waitcnt vmcnt(0)" ::: "memory");
            __syncthreads();  // (d) all stores drained
            if (tid == 0)
                __hip_atomic_fetch_add(cnt_g, 1, __ATOMIC_RELAXED, AG);
        }
    }

    cbuf[(size_t)bglob * H_ + unit] = creg;
}

// ---- final FC ----
extern "C" __global__ void __launch_bounds__(128)
fc_kernel(const float* __restrict__ hbuf, const float* __restrict__ fcw,
          const float* __restrict__ fcb, float* __restrict__ out) {
    __shared__ float wsm[256];
    const int tid = threadIdx.x;
    const int b = blockIdx.x;
    if (tid < 64) ((float4*)wsm)[tid] = ((const float4*)fcw)[tid];
    __syncthreads();
    if (tid < T_) {
        const float4* h4p = (const float4*)(hbuf + ((size_t)b * T_ + tid) * H_);
        const float4* w4p = (const float4*)wsm;
        float acc = fcb[0];
        #pragma unroll 8
        for (int k4 = 0; k4 < 64; ++k4) {
            float4 h4 = h4p[k4], w4 = w4p[k4];
            acc += h4.x * w4.x + h4.y * w4.y + h4.z * w4.z + h4.w * w4.w;
        }
        out[b * T_ + tid] = acc;
    }
}

extern "C" void kernel_launch(void* const* d_in, const int* in_sizes, int n_in,
                              void* d_out, int out_size, void* d_ws, size_t ws_size,
                              hipStream_t stream) {
    (void)in_sizes; (void)n_in; (void)out_size; (void)ws_size;
    const float* x    = (const float*)d_in[0];
    const float* Wih0 = (const float*)d_in[1];
    const float* Wihr = (const float*)d_in[2];
    const float* Whh  = (const float*)d_in[3];
    const float* bih  = (const float*)d_in[4];
    const float* bhh  = (const float*)d_in[5];
    const float* fcw  = (const float*)d_in[6];
    const float* fcb  = (const float*)d_in[7];
    float* out = (float*)d_out;
    float* ws  = (float*)d_ws;

    float* xp   = ws;
    float* hbuf = ws + XP_FLOATS;
    float* cbuf = hbuf + HBUF_FLOATS;
    float* wg   = cbuf + CBUF_FLOATS;
    float* hx   = wg + WG_FLOATS;
    int*   cnt  = (int*)(ws + CNT_OFF_FLOATS);

    hipMemsetAsync(cnt, 0, 32 * 32 * sizeof(int), stream);
    hipLaunchKernelGGL(wt_kernel, dim3(WG_FLOATS / 256), dim3(256), 0, stream, Whh, wg);

    for (int l = 0; l < L_; ++l) {
        const int K = (l == 0) ? IN_ : H_;
        const float* src = (l == 0) ? x : hbuf;
        const float* Wih = (l == 0) ? Wih0 : (Wihr + (size_t)(l - 1) * G_ * H_);
        const float* Wg_l = wg + (size_t)l * (G_ * H_);
        for (int ch = 0; ch < NCH_; ++ch) {
            const int t0 = ch * TC_;
            const int chkb = (l * NCH_ + ch) * (TC_ - 1);
            hipLaunchKernelGGL(proj_kernel, dim3(1024), dim3(256), 0, stream,
                               src, Wih, bih + l * G_, bhh + l * G_, xp, K, t0);
            hipLaunchKernelGGL(rec2_kernel, dim3(256), dim3(256), 157696, stream,
                               xp, Wg_l, hbuf, cbuf, hx, cnt, t0, chkb, ch == 0 ? 1 : 0);
        }
    }
    hipLaunchKernelGGL(fc_kernel, dim3(B_), dim3(128), 0, stream, hbuf, fcw, fcb, out);
}